// Round 18
// baseline (494.384 us; speedup 1.0000x reference)
//
#include <hip/hip_runtime.h>
#include <math.h>

// RALALinearAttention on MI355X — round 18.
// r17 = 441us. GEMM instruction audit: 24 LDS-b128/wave/iter (96KB/block) =
// 768cy vs 233cy MFMA -> LDS-BW bound (hence MfmaUtil stuck at 23%).
// r18: B packed FRAGMENT-MAJOR in prologue ([n16][k32][lane][8]); B fragments
// load direct from global (1KB coalesced, L2-resident) -> B leaves LDS
// entirely. LDS/iter halves (48KB/block), LDS size 40->20.5KB.
constexpr int B   = 16;
constexpr int IH  = 64;
constexpr int IW  = 64;
constexpr int C   = 256;
constexpr int NH  = 8;
constexpr int HD  = 32;
constexpr int N   = IH * IW;    // 4096
constexpr int C4  = 4 * C;      // 1024
constexpr int KVP_STRIDE = 1060; // 1024 kv + 32 km + mx + sum, padded

using f16x8 = __attribute__((ext_vector_type(8))) _Float16;
using f32x4 = __attribute__((ext_vector_type(4))) float;

// ---- prologue: rope tables + fragment-major packed weight splits -----------
// pack layout: idx = ((n16*8 + k32)*64 + lg*16 + lr)*8 + j
//   n16 = n/16, lr = n%16, k32 = k/32, lg = (k%32)/8, j = k%8
__global__ void k_prologue(const float* __restrict__ w_qkvo,
                           const float* __restrict__ w_proj,
                           float* __restrict__ cosT, float* __restrict__ sinT,
                           _Float16* __restrict__ wqh, _Float16* __restrict__ wql,
                           _Float16* __restrict__ wph, _Float16* __restrict__ wpl) {
  int bid = blockIdx.x;
  int tid = threadIdx.x;
  if (bid < 256) {                       // rope tables: N*16 entries
    int t = bid * 256 + tid;
    int j = t & 15, pix = t >> 4;
    int y = pix >> 6, x = pix & 63;
    int jj = j & 7;
    double theta = pow(10000.0, -(double)jj / 8.0);
    double pos = (j < 8) ? (double)y : (double)x;
    double ang = pos * theta;
    cosT[t] = (float)cos(ang);
    sinT[t] = (float)sin(ang);
  } else if (bid < 256 + C4) {           // pack w_qkvo column n
    int n = bid - 256;
    int k = tid;
    float v = w_qkvo[(size_t)k * C4 + n];
    _Float16 h = (_Float16)v;
    size_t idx = ((size_t)((n >> 4) * 8 + (k >> 5)) * 64 +
                  (((k >> 3) & 3) * 16 + (n & 15))) * 8 + (k & 7);
    wqh[idx] = h;
    wql[idx] = (_Float16)(v - (float)h);
  } else {                               // pack w_proj column n
    int n = bid - 256 - C4;
    int k = tid;
    float v = w_proj[(size_t)k * C + n];
    _Float16 h = (_Float16)v;
    size_t idx = ((size_t)((n >> 4) * 8 + (k >> 5)) * 64 +
                  (((k >> 3) & 3) * 16 + (n & 15))) * 8 + (k & 7);
    wph[idx] = h;
    wpl[idx] = (_Float16)(v - (float)h);
  }
}

// --------------- split-f16 MFMA GEMM, B-frags direct from packed global -----
// 128x128 tile, 4 waves (2x2), K=256, BK=32, 3-product Ootomo split.
// A: f32 -> h/l in staging (LDS, stride 40, depth-1 reg prefetch).
// B: fragment-major packed f16 (wave reads 1KB coalesced, L2-resident).
__global__ __launch_bounds__(256) void k_gemm_split(
    const float* __restrict__ A, int lda,
    const _Float16* __restrict__ BhP, const _Float16* __restrict__ BlP,
    const float* __restrict__ bias, float* __restrict__ Cm, int ldc,
    int nelu, float* __restrict__ qpart) {
  __shared__ _Float16 lds[2 * 5120];          // Ah | Al, stride 40 (20.5KB)
  _Float16* AhL = lds;
  _Float16* AlL = lds + 5120;
  int t = threadIdx.x;
  int m0 = blockIdx.x * 128, n0 = blockIdx.y * 128;
  int lane = t & 63;
  int wm = t >> 7, wn = (t >> 6) & 1;
  int lr = lane & 15, lg = lane >> 4;
  int srow = t >> 1, sseg = t & 1;            // one row-half per thread

  f32x4 acc[4][4] = {};

  const float* aP = &A[(size_t)(m0 + srow) * lda + sseg * 16];
  float4 ar0 = *(const float4*)(aP + 0);
  float4 ar1 = *(const float4*)(aP + 4);
  float4 ar2 = *(const float4*)(aP + 8);
  float4 ar3 = *(const float4*)(aP + 12);

  // packed-B base for this wave: n16 block = n0/16 + wn*4
  const int n16b = (n0 >> 4) + wn * 4;
  const _Float16* bhW = BhP + (size_t)lane * 8;
  const _Float16* blW = BlP + (size_t)lane * 8;

  for (int kc = 0; kc < 256; kc += 32) {
    {
      float av[16] = {ar0.x, ar0.y, ar0.z, ar0.w, ar1.x, ar1.y, ar1.z, ar1.w,
                      ar2.x, ar2.y, ar2.z, ar2.w, ar3.x, ar3.y, ar3.z, ar3.w};
      f16x8 h0, h1, l0, l1;
#pragma unroll
      for (int j = 0; j < 8; ++j) {
        _Float16 h = (_Float16)av[j];
        h0[j] = h; l0[j] = (_Float16)(av[j] - (float)h);
        _Float16 h2 = (_Float16)av[j + 8];
        h1[j] = h2; l1[j] = (_Float16)(av[j + 8] - (float)h2);
      }
      int d = srow * 40 + sseg * 16;
      *(f16x8*)&AhL[d] = h0; *(f16x8*)&AhL[d + 8] = h1;
      *(f16x8*)&AlL[d] = l0; *(f16x8*)&AlL[d + 8] = l1;
    }
    __syncthreads();

    if (kc + 32 < 256) {
      const float* aN = aP + kc + 32;
      ar0 = *(const float4*)(aN + 0);
      ar1 = *(const float4*)(aN + 4);
      ar2 = *(const float4*)(aN + 8);
      ar3 = *(const float4*)(aN + 12);
    }

    const int k32 = kc >> 5;
    // B fragments direct from packed global (issue early to cover L2 latency)
    f16x8 bh[4], bl[4];
#pragma unroll
    for (int ni = 0; ni < 4; ++ni) {
      size_t off = (size_t)((n16b + ni) * 8 + k32) * 512;
      bh[ni] = *(const f16x8*)(bhW + off);
      bl[ni] = *(const f16x8*)(blW + off);
    }
    f16x8 ah[4], al[4];
#pragma unroll
    for (int mi = 0; mi < 4; ++mi) {
      int ar = (wm * 64 + mi * 16 + lr) * 40 + lg * 8;
      ah[mi] = *(const f16x8*)&AhL[ar];
      al[mi] = *(const f16x8*)&AlL[ar];
    }
#pragma unroll
    for (int ni = 0; ni < 4; ++ni) {
#pragma unroll
      for (int mi = 0; mi < 4; ++mi) {
        acc[mi][ni] = __builtin_amdgcn_mfma_f32_16x16x32_f16(ah[mi], bh[ni], acc[mi][ni], 0, 0, 0);
        acc[mi][ni] = __builtin_amdgcn_mfma_f32_16x16x32_f16(al[mi], bh[ni], acc[mi][ni], 0, 0, 0);
        acc[mi][ni] = __builtin_amdgcn_mfma_f32_16x16x32_f16(ah[mi], bl[ni], acc[mi][ni], 0, 0, 0);
      }
    }
    __syncthreads();
  }

  // ---- epilogue: LDS transpose -> coalesced float4 stores (+ qmean qs) ----
  float* Cl = reinterpret_cast<float*>(lds);   // 32 x 132 f32 = 16.9KB <= 20.5KB
  int ri2 = t >> 3, c0 = (t & 7) << 4;
  bool doq = (qpart != nullptr) && (n0 < 256);  // block-uniform
  float qs[16] = {};
#pragma unroll
  for (int mi = 0; mi < 4; ++mi) {
#pragma unroll
    for (int ni = 0; ni < 4; ++ni) {
      int col = wn * 64 + ni * 16 + lr;
#pragma unroll
      for (int r = 0; r < 4; ++r)
        Cl[(wm * 16 + lg * 4 + r) * 132 + col] = acc[mi][ni][r];
    }
    __syncthreads();
    int grow = m0 + (ri2 >> 4) * 64 + mi * 16 + (ri2 & 15);
#pragma unroll
    for (int j = 0; j < 4; ++j) {
      int col = n0 + c0 + j * 4;
      float4 v = *(const float4*)&Cl[ri2 * 132 + c0 + j * 4];
      float4 bb = *(const float4*)&bias[col];
      v.x += bb.x; v.y += bb.y; v.z += bb.z; v.w += bb.w;
      if (col < nelu) {
        v.x = (v.x > 0.f) ? v.x + 1.f : expf(v.x);
        v.y = (v.y > 0.f) ? v.y + 1.f : expf(v.y);
        v.z = (v.z > 0.f) ? v.z + 1.f : expf(v.z);
        v.w = (v.w > 0.f) ? v.w + 1.f : expf(v.w);
      }
      if (doq) {
        qs[j * 4 + 0] += v.x; qs[j * 4 + 1] += v.y;
        qs[j * 4 + 2] += v.z; qs[j * 4 + 3] += v.w;
      }
      *(float4*)&Cm[(size_t)grow * ldc + col] = v;
    }
    __syncthreads();
  }
  if (doq) {
#pragma unroll
    for (int j = 0; j < 4; ++j) {
      float4 w4 = {qs[j*4+0], qs[j*4+1], qs[j*4+2], qs[j*4+3]};
      *(float4*)&Cl[ri2 * 132 + c0 + j * 4] = w4;
    }
    __syncthreads();
    if (t < 128) {
      float ssum = 0.f;
#pragma unroll
      for (int rr = 0; rr < 32; ++rr) ssum += Cl[rr * 132 + t];
      int b_local = m0 >> 12, rowblk = (m0 >> 7) & 31;
      qpart[(size_t)(b_local * 32 + rowblk) * 256 + n0 + t] = ssum;
    }
  }
}

// ---- merged kvflash + lepe: one dispatch, role by blockIdx ----------------
__global__ __launch_bounds__(256) void k_kvflash_lepe(
    const float* __restrict__ qkvo, const float* __restrict__ qpart,
    const float* __restrict__ cosT, const float* __restrict__ sinT,
    float* __restrict__ kvp,
    const float* __restrict__ lepe_w, const float* __restrict__ lepe_b,
    float* __restrict__ lepe_out, int b0, int kvN) {
  __shared__ float qm[32];
  __shared__ float sL[512];
  __shared__ float red[256];
  __shared__ float ktG[4][32][36];
  __shared__ float vtG[4][32][36];
  int bid = blockIdx.x;
  int t = threadIdx.x;

  if (bid >= kvN) {
    // ------------------------- LEPE branch -------------------------
    int blk = bid - kvN;
    int b = blk >> 8, rem = blk & 255;
    int y = rem >> 2, x0 = (rem & 3) << 4;
    int c = t;
    float w[25];
#pragma unroll
    for (int i = 0; i < 25; ++i) w[i] = lepe_w[c * 25 + i];
    float bias = lepe_b[c];
    float acc[16];
#pragma unroll
    for (int p = 0; p < 16; ++p) acc[p] = bias;
#pragma unroll
    for (int dy = 0; dy < 5; ++dy) {
      int yy = y + dy - 2;
      if (yy < 0 || yy >= IH) continue;
      size_t rowb = (size_t)(b * N + (yy << 6)) * C4 + 512 + c;
#pragma unroll
      for (int dx = 0; dx < 5; ++dx) {
        float wv = w[dy * 5 + dx];
#pragma unroll
        for (int p = 0; p < 16; ++p) {
          int xx = x0 + p + dx - 2;
          if (xx < 0 || xx >= IW) continue;
          acc[p] = fmaf(qkvo[rowb + (size_t)xx * C4], wv, acc[p]);
        }
      }
    }
#pragma unroll
    for (int p = 0; p < 16; ++p)
      lepe_out[(size_t)((b0 + b) * N + (y << 6) + x0 + p) * C + c] = acc[p];
    return;
  }

  // ------------------------- KV-flash branch -------------------------
  int bh = bid >> 3, chunk = bid & 7;
  int b = bh >> 3, h = bh & 7;
  int nbase = chunk << 9;

  // phase 0: qmean from GEMM1 partials
  if (t < 32) {
    float s = 0.f;
#pragma unroll
    for (int rb = 0; rb < 32; ++rb)
      s += qpart[(size_t)(b * 32 + rb) * 256 + (h << 5) + t];
    qm[t] = s * (1.0f / N) * 0.1767766952966369f;
  }
  __syncthreads();

  // phase A: scores, chunk max and exp-sum
  float qmr[32];
#pragma unroll
  for (int i = 0; i < 32; ++i) qmr[i] = qm[i];
  float mx = -3.4e38f;
#pragma unroll
  for (int i = 0; i < 2; ++i) {
    int n = nbase + t + i * 256;
    const float* kp = &qkvo[(size_t)(b * N + n) * C4 + 256 + (h << 5)];
    float dot = 0.f;
#pragma unroll
    for (int j = 0; j < 8; ++j) {
      float4 k4 = *(const float4*)(kp + (j << 2));
      dot += k4.x * qmr[j*4] + k4.y * qmr[j*4+1] + k4.z * qmr[j*4+2] + k4.w * qmr[j*4+3];
    }
    sL[t + i * 256] = dot;
    mx = fmaxf(mx, dot);
  }
  red[t] = mx; __syncthreads();
  for (int off = 128; off > 0; off >>= 1) {
    if (t < off) red[t] = fmaxf(red[t], red[t + off]);
    __syncthreads();
  }
  float mx_c = red[0];
  __syncthreads();
  float psum = expf(sL[t] - mx_c) + expf(sL[t + 256] - mx_c);
  red[t] = psum; __syncthreads();
  for (int off = 128; off > 0; off >>= 1) {
    if (t < off) red[t] += red[t + off];
    __syncthreads();
  }
  float sum_c = red[0];

  // phase B: register-tiled kv
  int sg = t >> 6;
  int lane = t & 63;
  int d0 = (lane >> 3) << 2;
  int e0 = (lane & 7) << 2;
  int srow_l = (t >> 1) & 31;
  int sdh = t & 1;
  float acc[4][4] = {};
  float km16[16] = {};

  for (int s = 0; s < 4; ++s) {
    int nloc = sg * 128 + s * 32 + srow_l;
    int n = nbase + nloc;
    const float* kp = &qkvo[(size_t)(b * N + n) * C4 + 256 + (h << 5) + sdh * 16];
    const float* vp = kp + 256;
    float ef = expf(sL[nloc] - mx_c);
    float kl[16], vl[16];
#pragma unroll
    for (int j4 = 0; j4 < 4; ++j4) {
      float4 k4 = *(const float4*)(kp + (j4 << 2));
      float4 v4 = *(const float4*)(vp + (j4 << 2));
      k4.x *= ef; k4.y *= ef; k4.z *= ef; k4.w *= ef;
      km16[j4*4+0] += k4.x; km16[j4*4+1] += k4.y;
      km16[j4*4+2] += k4.z; km16[j4*4+3] += k4.w;
      kl[j4*4+0] = k4.x; kl[j4*4+1] = k4.y; kl[j4*4+2] = k4.z; kl[j4*4+3] = k4.w;
      vl[j4*4+0] = v4.x; vl[j4*4+1] = v4.y; vl[j4*4+2] = v4.z; vl[j4*4+3] = v4.w;
    }
#pragma unroll
    for (int p = 0; p < 8; ++p) {
      float cc = cosT[(n << 4) + sdh * 8 + p];
      float sn = sinT[(n << 4) + sdh * 8 + p];
      float kr = kl[2*p], ki = kl[2*p+1];
      kl[2*p]   = kr * cc - ki * sn;
      kl[2*p+1] = kr * sn + ki * cc;
    }
#pragma unroll
    for (int j4 = 0; j4 < 4; ++j4) {
      float4 kw = {kl[j4*4+0], kl[j4*4+1], kl[j4*4+2], kl[j4*4+3]};
      float4 vw = {vl[j4*4+0], vl[j4*4+1], vl[j4*4+2], vl[j4*4+3]};
      *(float4*)&ktG[sg][srow_l][sdh*16 + (j4 << 2)] = kw;
      *(float4*)&vtG[sg][srow_l][sdh*16 + (j4 << 2)] = vw;
    }
    __syncthreads();
    __builtin_amdgcn_s_setprio(1);
#pragma unroll
    for (int nn = 0; nn < 32; ++nn) {
      float4 k4 = *(const float4*)&ktG[sg][nn][d0];
      float4 v4 = *(const float4*)&vtG[sg][nn][e0];
      float kv_[4] = {k4.x, k4.y, k4.z, k4.w};
      float vv_[4] = {v4.x, v4.y, v4.z, v4.w};
#pragma unroll
      for (int i = 0; i < 4; ++i)
#pragma unroll
        for (int j = 0; j < 4; ++j)
          acc[i][j] = fmaf(kv_[i], vv_[j], acc[i][j]);
    }
    __builtin_amdgcn_s_setprio(0);
    __syncthreads();
  }

  // merge kv partials (overlay on ktG)
  float* mrg = &ktG[0][0][0];
#pragma unroll
  for (int i = 0; i < 4; ++i)
#pragma unroll
    for (int j = 0; j < 4; ++j)
      mrg[sg * 1024 + (d0 + i) * 32 + (e0 + j)] = acc[i][j];
  __syncthreads();
  size_t o = (size_t)(bh * 8 + chunk) * KVP_STRIDE;
  {
    int idx = t << 2;
    float4 r;
    r.x = mrg[idx+0] + mrg[1024+idx+0] + mrg[2048+idx+0] + mrg[3072+idx+0];
    r.y = mrg[idx+1] + mrg[1024+idx+1] + mrg[2048+idx+1] + mrg[3072+idx+1];
    r.z = mrg[idx+2] + mrg[1024+idx+2] + mrg[2048+idx+2] + mrg[3072+idx+2];
    r.w = mrg[idx+3] + mrg[1024+idx+3] + mrg[2048+idx+3] + mrg[3072+idx+3];
    kvp[o + idx + 0] = r.x; kvp[o + idx + 1] = r.y;
    kvp[o + idx + 2] = r.z; kvp[o + idx + 3] = r.w;
  }
  // merge km (overlay on vtG)
  float* kmb = &vtG[0][0][0];
#pragma unroll
  for (int j = 0; j < 16; ++j) kmb[t * 16 + j] = km16[j];
  __syncthreads();
  if (t < 32) {
    int dh = t >> 4, dj = t & 15;
    float ssum = 0.f;
    for (int r = 0; r < 128; ++r) ssum += kmb[((r << 1) + dh) * 16 + dj];
    kvp[o + 1024 + t] = ssum;
  }
  if (t == 0) {
    kvp[o + 1056] = mx_c;
    kvp[o + 1057] = sum_c;
  }
}

// -- opre = ((rope(q) @ kv) * z + lepe) * o; LSE merge fused; 2 rows/thread --
__global__ __launch_bounds__(256) void k_out_combine(
    float* __restrict__ qkvo, const float* __restrict__ kvp,
    const float* __restrict__ cosT, const float* __restrict__ sinT,
    const float* __restrict__ lepe, int b0) {
  __shared__ float kvs[1024];
  __shared__ float kms[32];
  __shared__ float fcs[8];
  int bh = blockIdx.x, chunk = blockIdx.y;   // chunk in [0,8): rows n, n+2048
  int b = bh >> 3, h = bh & 7;
  int t = threadIdx.x;
  if (t == 0) {
    float mxs[8], sums[8];
    float mx = -3.4e38f;
#pragma unroll
    for (int c = 0; c < 8; ++c) {
      size_t o = (size_t)(bh * 8 + c) * KVP_STRIDE;
      mxs[c] = kvp[o + 1056];
      sums[c] = kvp[o + 1057];
      mx = fmaxf(mx, mxs[c]);
    }
    float T = 0.f;
#pragma unroll
    for (int c = 0; c < 8; ++c) T += sums[c] * expf(mxs[c] - mx);
    float invT = 1.0f / T;
#pragma unroll
    for (int c = 0; c < 8; ++c) fcs[c] = expf(mxs[c] - mx) * invT;
  }
  __syncthreads();
  {
    int idx = t << 2;
    size_t o0 = (size_t)(bh * 8) * KVP_STRIDE + idx;
    float4 r = {0.f, 0.f, 0.f, 0.f};
#pragma unroll
    for (int c = 0; c < 8; ++c) {
      float4 p = *(const float4*)&kvp[o0 + (size_t)c * KVP_STRIDE];
      float f = fcs[c];
      r.x += p.x * f; r.y += p.y * f; r.z += p.z * f; r.w += p.w * f;
    }
    *(float4*)&kvs[idx] = r;
    if (t < 32) {
      float s = 0.f;
#pragma unroll
      for (int c = 0; c < 8; ++c)
        s += kvp[(size_t)(bh * 8 + c) * KVP_STRIDE + 1024 + t] * fcs[c];
      kms[t] = s;
    }
  }
  __syncthreads();
  int n1 = (chunk << 8) + t;
  int n2 = n1 + 2048;
  size_t rb1 = (size_t)(b * N + n1) * C4;
  size_t rb2 = (size_t)(b * N + n2) * C4;
  float q1[32], q2[32];
#pragma unroll
  for (int i = 0; i < 8; ++i) {
    float4 a4 = *(const float4*)&qkvo[rb1 + (h << 5) + (i << 2)];
    float4 b4 = *(const float4*)&qkvo[rb2 + (h << 5) + (i << 2)];
    q1[i*4+0] = a4.x; q1[i*4+1] = a4.y; q1[i*4+2] = a4.z; q1[i*4+3] = a4.w;
    q2[i*4+0] = b4.x; q2[i*4+1] = b4.y; q2[i*4+2] = b4.z; q2[i*4+3] = b4.w;
  }
  float dot1 = 0.f, dot2 = 0.f;
#pragma unroll
  for (int dd = 0; dd < 32; ++dd) {
    dot1 += q1[dd] * kms[dd];
    dot2 += q2[dd] * kms[dd];
  }
  float zv1 = 1.0f / (dot1 + 1e-6f);
  float zv2 = 1.0f / (dot2 + 1e-6f);
#pragma unroll
  for (int j = 0; j < 16; ++j) {
    float c1 = cosT[(n1 << 4) + j], s1 = sinT[(n1 << 4) + j];
    float qr = q1[2*j], qi = q1[2*j+1];
    q1[2*j]   = qr * c1 - qi * s1;
    q1[2*j+1] = qr * s1 + qi * c1;
    float c2 = cosT[(n2 << 4) + j], s2 = sinT[(n2 << 4) + j];
    float kr = q2[2*j], ki = q2[2*j+1];
    q2[2*j]   = kr * c2 - ki * s2;
    q2[2*j+1] = kr * s2 + ki * c2;
  }
  size_t oc1 = (size_t)((b0 + b) * N + n1) * C + (h << 5);
  size_t oc2 = (size_t)((b0 + b) * N + n2) * C + (h << 5);
#pragma unroll
  for (int e4 = 0; e4 < 8; ++e4) {
    float a1x = 0, a1y = 0, a1z = 0, a1w = 0;
    float a2x = 0, a2y = 0, a2z = 0, a2w = 0;
#pragma unroll
    for (int dd = 0; dd < 32; ++dd) {
      float4 kv4 = *(const float4*)&kvs[(dd << 5) + (e4 << 2)];
      float qa = q1[dd], qb = q2[dd];
      a1x = fmaf(qa, kv4.x, a1x); a1y = fmaf(qa, kv4.y, a1y);
      a1z = fmaf(qa, kv4.z, a1z); a1w = fmaf(qa, kv4.w, a1w);
      a2x = fmaf(qb, kv4.x, a2x); a2y = fmaf(qb, kv4.y, a2y);
      a2z = fmaf(qb, kv4.z, a2z); a2w = fmaf(qb, kv4.w, a2w);
    }
    float4 lp1 = *(const float4*)&lepe[oc1 + (e4 << 2)];
    float4 ov1 = *(const float4*)&qkvo[rb1 + 768 + (h << 5) + (e4 << 2)];
    float4 r1;
    r1.x = (a1x * zv1 + lp1.x) * ov1.x;
    r1.y = (a1y * zv1 + lp1.y) * ov1.y;
    r1.z = (a1z * zv1 + lp1.z) * ov1.z;
    r1.w = (a1w * zv1 + lp1.w) * ov1.w;
    *(float4*)&qkvo[rb1 + (h << 5) + (e4 << 2)] = r1;
    float4 lp2 = *(const float4*)&lepe[oc2 + (e4 << 2)];
    float4 ov2 = *(const float4*)&qkvo[rb2 + 768 + (h << 5) + (e4 << 2)];
    float4 r2;
    r2.x = (a2x * zv2 + lp2.x) * ov2.x;
    r2.y = (a2y * zv2 + lp2.y) * ov2.y;
    r2.z = (a2z * zv2 + lp2.z) * ov2.z;
    r2.w = (a2w * zv2 + lp2.w) * ov2.w;
    *(float4*)&qkvo[rb2 + (h << 5) + (e4 << 2)] = r2;
  }
}

// ---------------------------------------------------------------------------
static inline size_t ws_bytes_needed(int bpp) {
  size_t pn = (size_t)bpp * N;
  size_t f32c = pn * C4                            // qkvo
              + (size_t)bpp * 32 * 256             // qmean partials
              + (size_t)bpp * NH * 8 * KVP_STRIDE  // kv+km+stats partials
              + (size_t)N * 16 * 2;                // cos/sin
  size_t f16c = (size_t)C * C4 * 2                 // wq packed splits
              + (size_t)C * C * 2;                 // wp packed splits
  return f32c * 4 + f16c * 2;
}

extern "C" void kernel_launch(void* const* d_in, const int* in_sizes, int n_in,
                              void* d_out, int out_size, void* d_ws, size_t ws_size,
                              hipStream_t stream) {
  const float* x      = (const float*)d_in[0];
  const float* w_qkvo = (const float*)d_in[1];
  const float* b_qkvo = (const float*)d_in[2];
  const float* lepe_w = (const float*)d_in[3];
  const float* lepe_b = (const float*)d_in[4];
  const float* w_proj = (const float*)d_in[5];
  const float* b_proj = (const float*)d_in[6];
  float* out = (float*)d_out;
  float* ws  = (float*)d_ws;

  int bpp = 2;
  if (ws_bytes_needed(16) <= ws_size) bpp = 16;
  else if (ws_bytes_needed(8) <= ws_size) bpp = 8;
  else if (ws_bytes_needed(4) <= ws_size) bpp = 4;

  size_t pn = (size_t)bpp * N;
  int nbh = bpp * NH;
  float* qkvo  = ws;
  float* qpart = qkvo  + pn * C4;
  float* kvp   = qpart + (size_t)bpp * 32 * 256;
  float* cosT  = kvp   + (size_t)nbh * 8 * KVP_STRIDE;
  float* sinT  = cosT  + (size_t)N * 16;
  _Float16* wqh = (_Float16*)(sinT + (size_t)N * 16);
  _Float16* wql = wqh + (size_t)C * C4;
  _Float16* wph = wql + (size_t)C * C4;
  _Float16* wpl = wph + (size_t)C * C;

  k_prologue<<<256 + C4 + C, 256, 0, stream>>>(w_qkvo, w_proj, cosT, sinT,
                                               wqh, wql, wph, wpl);

  for (int b0 = 0; b0 < B; b0 += bpp) {
    // GEMM1: qkvo = x@w_qkvo + b, elu on cols<512, qmean partials fused
    k_gemm_split<<<dim3(pn / 128, C4 / 128), 256, 0, stream>>>(
        x + (size_t)b0 * N * C, C, wqh, wql, b_qkvo, qkvo, C4, 512, qpart);
    // merged: flash kv (nbh*8 blocks) + lepe (bpp*256 blocks)
    int kvN = nbh * 8;
    k_kvflash_lepe<<<kvN + bpp * 256, 256, 0, stream>>>(
        qkvo, qpart, cosT, sinT, kvp, lepe_w, lepe_b, out, b0, kvN);
    k_out_combine<<<dim3(nbh, 8), 256, 0, stream>>>(qkvo, kvp, cosT, sinT, out, b0);
    // GEMM2: out = opre @ w_proj + b (A = f32 opre in qkvo q-slot)
    k_gemm_split<<<dim3(pn / 128, C / 128), 256, 0, stream>>>(
        qkvo, C4, wph, wpl, b_proj, out + (size_t)b0 * N * C, C, 0, nullptr);
  }
}

// Round 19
// 441.106 us; speedup vs baseline: 1.1208x; 1.1208x over previous
//
#include <hip/hip_runtime.h>
#include <math.h>

// RALALinearAttention on MI355X — round 19 = exact r17 restore (441us best).
// r18 disproved the LDS-BW theory: B-direct-from-global halved LDS traffic
// but exposed ~200cy L2 latency per iter on the critical path (91->109us).
// The r17 GEMM structure (all operands LDS, staging prefetched 1 iter ahead
// in registers) is the proven optimum of this structure class.
constexpr int B   = 16;
constexpr int IH  = 64;
constexpr int IW  = 64;
constexpr int C   = 256;
constexpr int NH  = 8;
constexpr int HD  = 32;
constexpr int N   = IH * IW;    // 4096
constexpr int C4  = 4 * C;      // 1024
constexpr int KVP_STRIDE = 1060; // 1024 kv + 32 km + mx + sum, padded

using f16x8 = __attribute__((ext_vector_type(8))) _Float16;
using f32x4 = __attribute__((ext_vector_type(4))) float;

// ---- prologue: rope tables + transposed weight splits, one dispatch --------
__global__ void k_prologue(const float* __restrict__ w_qkvo,
                           const float* __restrict__ w_proj,
                           float* __restrict__ cosT, float* __restrict__ sinT,
                           _Float16* __restrict__ wqh, _Float16* __restrict__ wql,
                           _Float16* __restrict__ wph, _Float16* __restrict__ wpl) {
  int bid = blockIdx.x;
  int tid = threadIdx.x;
  if (bid < 256) {                       // rope tables: N*16 entries
    int t = bid * 256 + tid;
    int j = t & 15, pix = t >> 4;
    int y = pix >> 6, x = pix & 63;
    int jj = j & 7;
    double theta = pow(10000.0, -(double)jj / 8.0);
    double pos = (j < 8) ? (double)y : (double)x;
    double ang = pos * theta;
    cosT[t] = (float)cos(ang);
    sinT[t] = (float)sin(ang);
  } else if (bid < 256 + C4) {           // split w_qkvo column -> [n][256]
    int n = bid - 256;
    float v = w_qkvo[(size_t)tid * C4 + n];
    _Float16 h = (_Float16)v;
    wqh[(size_t)n * 256 + tid] = h;
    wql[(size_t)n * 256 + tid] = (_Float16)(v - (float)h);
  } else {                               // split w_proj column
    int n = bid - 256 - C4;
    float v = w_proj[(size_t)tid * C + n];
    _Float16 h = (_Float16)v;
    wph[(size_t)n * 256 + tid] = h;
    wpl[(size_t)n * 256 + tid] = (_Float16)(v - (float)h);
  }
}

// --------------- split-f16 MFMA GEMM (r13 depth-1, stride 40) + qmean -------
__global__ __launch_bounds__(256) void k_gemm_split(
    const float* __restrict__ A, int lda,
    const _Float16* __restrict__ BhT, const _Float16* __restrict__ BlT,
    const float* __restrict__ bias, float* __restrict__ Cm, int ldc,
    int nelu, float* __restrict__ qpart) {
  __shared__ _Float16 lds[4 * 5120];          // Ah | Al | Bh | Bl, stride 40
  _Float16* AhL = lds;
  _Float16* AlL = lds + 5120;
  _Float16* BhL = lds + 10240;
  _Float16* BlL = lds + 15360;
  int t = threadIdx.x;
  int m0 = blockIdx.x * 128, n0 = blockIdx.y * 128;
  int lane = t & 63;
  int wm = t >> 7, wn = (t >> 6) & 1;
  int lr = lane & 15, lg = lane >> 4;
  int srow = t >> 1, sseg = t & 1;            // one row-half per thread

  f32x4 acc[4][4] = {};

  const float* aP = &A[(size_t)(m0 + srow) * lda + sseg * 16];
  const _Float16* bhP = &BhT[(size_t)(n0 + srow) * 256 + sseg * 16];
  const _Float16* blP = &BlT[(size_t)(n0 + srow) * 256 + sseg * 16];
  float4 ar0 = *(const float4*)(aP + 0);
  float4 ar1 = *(const float4*)(aP + 4);
  float4 ar2 = *(const float4*)(aP + 8);
  float4 ar3 = *(const float4*)(aP + 12);
  f16x8 brh0 = *(const f16x8*)(bhP + 0);
  f16x8 brh1 = *(const f16x8*)(bhP + 8);
  f16x8 brl0 = *(const f16x8*)(blP + 0);
  f16x8 brl1 = *(const f16x8*)(blP + 8);

  for (int kc = 0; kc < 256; kc += 32) {
    {
      float av[16] = {ar0.x, ar0.y, ar0.z, ar0.w, ar1.x, ar1.y, ar1.z, ar1.w,
                      ar2.x, ar2.y, ar2.z, ar2.w, ar3.x, ar3.y, ar3.z, ar3.w};
      f16x8 h0, h1, l0, l1;
#pragma unroll
      for (int j = 0; j < 8; ++j) {
        _Float16 h = (_Float16)av[j];
        h0[j] = h; l0[j] = (_Float16)(av[j] - (float)h);
        _Float16 h2 = (_Float16)av[j + 8];
        h1[j] = h2; l1[j] = (_Float16)(av[j + 8] - (float)h2);
      }
      int d = srow * 40 + sseg * 16;
      *(f16x8*)&AhL[d] = h0; *(f16x8*)&AhL[d + 8] = h1;
      *(f16x8*)&AlL[d] = l0; *(f16x8*)&AlL[d + 8] = l1;
      *(f16x8*)&BhL[d] = brh0; *(f16x8*)&BhL[d + 8] = brh1;
      *(f16x8*)&BlL[d] = brl0; *(f16x8*)&BlL[d + 8] = brl1;
    }
    __syncthreads();

    if (kc + 32 < 256) {
      const float* aN = aP + kc + 32;
      const _Float16* bhN = bhP + kc + 32;
      const _Float16* blN = blP + kc + 32;
      ar0 = *(const float4*)(aN + 0);
      ar1 = *(const float4*)(aN + 4);
      ar2 = *(const float4*)(aN + 8);
      ar3 = *(const float4*)(aN + 12);
      brh0 = *(const f16x8*)(bhN + 0);
      brh1 = *(const f16x8*)(bhN + 8);
      brl0 = *(const f16x8*)(blN + 0);
      brl1 = *(const f16x8*)(blN + 8);
    }

    f16x8 ah[4], al[4];
#pragma unroll
    for (int mi = 0; mi < 4; ++mi) {
      int ar = (wm * 64 + mi * 16 + lr) * 40 + lg * 8;
      ah[mi] = *(const f16x8*)&AhL[ar];
      al[mi] = *(const f16x8*)&AlL[ar];
    }
#pragma unroll
    for (int ni = 0; ni < 4; ++ni) {
      int br = (wn * 64 + ni * 16 + lr) * 40 + lg * 8;
      f16x8 bh = *(const f16x8*)&BhL[br];
      f16x8 bl = *(const f16x8*)&BlL[br];
#pragma unroll
      for (int mi = 0; mi < 4; ++mi) {
        acc[mi][ni] = __builtin_amdgcn_mfma_f32_16x16x32_f16(ah[mi], bh, acc[mi][ni], 0, 0, 0);
        acc[mi][ni] = __builtin_amdgcn_mfma_f32_16x16x32_f16(al[mi], bh, acc[mi][ni], 0, 0, 0);
        acc[mi][ni] = __builtin_amdgcn_mfma_f32_16x16x32_f16(ah[mi], bl, acc[mi][ni], 0, 0, 0);
      }
    }
    __syncthreads();
  }

  // ---- epilogue: LDS transpose -> coalesced float4 stores (+ qmean qs) ----
  float* Cl = reinterpret_cast<float*>(lds);   // 32 x 132 f32
  int ri2 = t >> 3, c0 = (t & 7) << 4;
  bool doq = (qpart != nullptr) && (n0 < 256);  // block-uniform
  float qs[16] = {};
#pragma unroll
  for (int mi = 0; mi < 4; ++mi) {
#pragma unroll
    for (int ni = 0; ni < 4; ++ni) {
      int col = wn * 64 + ni * 16 + lr;
#pragma unroll
      for (int r = 0; r < 4; ++r)
        Cl[(wm * 16 + lg * 4 + r) * 132 + col] = acc[mi][ni][r];
    }
    __syncthreads();
    int grow = m0 + (ri2 >> 4) * 64 + mi * 16 + (ri2 & 15);
#pragma unroll
    for (int j = 0; j < 4; ++j) {
      int col = n0 + c0 + j * 4;
      float4 v = *(const float4*)&Cl[ri2 * 132 + c0 + j * 4];
      float4 bb = *(const float4*)&bias[col];
      v.x += bb.x; v.y += bb.y; v.z += bb.z; v.w += bb.w;
      if (col < nelu) {
        v.x = (v.x > 0.f) ? v.x + 1.f : expf(v.x);
        v.y = (v.y > 0.f) ? v.y + 1.f : expf(v.y);
        v.z = (v.z > 0.f) ? v.z + 1.f : expf(v.z);
        v.w = (v.w > 0.f) ? v.w + 1.f : expf(v.w);
      }
      if (doq) {
        qs[j * 4 + 0] += v.x; qs[j * 4 + 1] += v.y;
        qs[j * 4 + 2] += v.z; qs[j * 4 + 3] += v.w;
      }
      *(float4*)&Cm[(size_t)grow * ldc + col] = v;
    }
    __syncthreads();
  }
  if (doq) {
#pragma unroll
    for (int j = 0; j < 4; ++j) {
      float4 w4 = {qs[j*4+0], qs[j*4+1], qs[j*4+2], qs[j*4+3]};
      *(float4*)&Cl[ri2 * 132 + c0 + j * 4] = w4;
    }
    __syncthreads();
    if (t < 128) {
      float ssum = 0.f;
#pragma unroll
      for (int rr = 0; rr < 32; ++rr) ssum += Cl[rr * 132 + t];
      int b_local = m0 >> 12, rowblk = (m0 >> 7) & 31;
      qpart[(size_t)(b_local * 32 + rowblk) * 256 + n0 + t] = ssum;
    }
  }
}

// ---- merged kvflash + lepe: one dispatch, role by blockIdx ----------------
__global__ __launch_bounds__(256) void k_kvflash_lepe(
    const float* __restrict__ qkvo, const float* __restrict__ qpart,
    const float* __restrict__ cosT, const float* __restrict__ sinT,
    float* __restrict__ kvp,
    const float* __restrict__ lepe_w, const float* __restrict__ lepe_b,
    float* __restrict__ lepe_out, int b0, int kvN) {
  __shared__ float qm[32];
  __shared__ float sL[512];
  __shared__ float red[256];
  __shared__ float ktG[4][32][36];
  __shared__ float vtG[4][32][36];
  int bid = blockIdx.x;
  int t = threadIdx.x;

  if (bid >= kvN) {
    // ------------------------- LEPE branch -------------------------
    int blk = bid - kvN;
    int b = blk >> 8, rem = blk & 255;
    int y = rem >> 2, x0 = (rem & 3) << 4;
    int c = t;
    float w[25];
#pragma unroll
    for (int i = 0; i < 25; ++i) w[i] = lepe_w[c * 25 + i];
    float bias = lepe_b[c];
    float acc[16];
#pragma unroll
    for (int p = 0; p < 16; ++p) acc[p] = bias;
#pragma unroll
    for (int dy = 0; dy < 5; ++dy) {
      int yy = y + dy - 2;
      if (yy < 0 || yy >= IH) continue;
      size_t rowb = (size_t)(b * N + (yy << 6)) * C4 + 512 + c;
#pragma unroll
      for (int dx = 0; dx < 5; ++dx) {
        float wv = w[dy * 5 + dx];
#pragma unroll
        for (int p = 0; p < 16; ++p) {
          int xx = x0 + p + dx - 2;
          if (xx < 0 || xx >= IW) continue;
          acc[p] = fmaf(qkvo[rowb + (size_t)xx * C4], wv, acc[p]);
        }
      }
    }
#pragma unroll
    for (int p = 0; p < 16; ++p)
      lepe_out[(size_t)((b0 + b) * N + (y << 6) + x0 + p) * C + c] = acc[p];
    return;
  }

  // ------------------------- KV-flash branch -------------------------
  int bh = bid >> 3, chunk = bid & 7;
  int b = bh >> 3, h = bh & 7;
  int nbase = chunk << 9;

  // phase 0: qmean from GEMM1 partials
  if (t < 32) {
    float s = 0.f;
#pragma unroll
    for (int rb = 0; rb < 32; ++rb)
      s += qpart[(size_t)(b * 32 + rb) * 256 + (h << 5) + t];
    qm[t] = s * (1.0f / N) * 0.1767766952966369f;
  }
  __syncthreads();

  // phase A: scores, chunk max and exp-sum
  float qmr[32];
#pragma unroll
  for (int i = 0; i < 32; ++i) qmr[i] = qm[i];
  float mx = -3.4e38f;
#pragma unroll
  for (int i = 0; i < 2; ++i) {
    int n = nbase + t + i * 256;
    const float* kp = &qkvo[(size_t)(b * N + n) * C4 + 256 + (h << 5)];
    float dot = 0.f;
#pragma unroll
    for (int j = 0; j < 8; ++j) {
      float4 k4 = *(const float4*)(kp + (j << 2));
      dot += k4.x * qmr[j*4] + k4.y * qmr[j*4+1] + k4.z * qmr[j*4+2] + k4.w * qmr[j*4+3];
    }
    sL[t + i * 256] = dot;
    mx = fmaxf(mx, dot);
  }
  red[t] = mx; __syncthreads();
  for (int off = 128; off > 0; off >>= 1) {
    if (t < off) red[t] = fmaxf(red[t], red[t + off]);
    __syncthreads();
  }
  float mx_c = red[0];
  __syncthreads();
  float psum = expf(sL[t] - mx_c) + expf(sL[t + 256] - mx_c);
  red[t] = psum; __syncthreads();
  for (int off = 128; off > 0; off >>= 1) {
    if (t < off) red[t] += red[t + off];
    __syncthreads();
  }
  float sum_c = red[0];

  // phase B: register-tiled kv
  int sg = t >> 6;
  int lane = t & 63;
  int d0 = (lane >> 3) << 2;
  int e0 = (lane & 7) << 2;
  int srow_l = (t >> 1) & 31;
  int sdh = t & 1;
  float acc[4][4] = {};
  float km16[16] = {};

  for (int s = 0; s < 4; ++s) {
    int nloc = sg * 128 + s * 32 + srow_l;
    int n = nbase + nloc;
    const float* kp = &qkvo[(size_t)(b * N + n) * C4 + 256 + (h << 5) + sdh * 16];
    const float* vp = kp + 256;
    float ef = expf(sL[nloc] - mx_c);
    float kl[16], vl[16];
#pragma unroll
    for (int j4 = 0; j4 < 4; ++j4) {
      float4 k4 = *(const float4*)(kp + (j4 << 2));
      float4 v4 = *(const float4*)(vp + (j4 << 2));
      k4.x *= ef; k4.y *= ef; k4.z *= ef; k4.w *= ef;
      km16[j4*4+0] += k4.x; km16[j4*4+1] += k4.y;
      km16[j4*4+2] += k4.z; km16[j4*4+3] += k4.w;
      kl[j4*4+0] = k4.x; kl[j4*4+1] = k4.y; kl[j4*4+2] = k4.z; kl[j4*4+3] = k4.w;
      vl[j4*4+0] = v4.x; vl[j4*4+1] = v4.y; vl[j4*4+2] = v4.z; vl[j4*4+3] = v4.w;
    }
#pragma unroll
    for (int p = 0; p < 8; ++p) {
      float cc = cosT[(n << 4) + sdh * 8 + p];
      float sn = sinT[(n << 4) + sdh * 8 + p];
      float kr = kl[2*p], ki = kl[2*p+1];
      kl[2*p]   = kr * cc - ki * sn;
      kl[2*p+1] = kr * sn + ki * cc;
    }
#pragma unroll
    for (int j4 = 0; j4 < 4; ++j4) {
      float4 kw = {kl[j4*4+0], kl[j4*4+1], kl[j4*4+2], kl[j4*4+3]};
      float4 vw = {vl[j4*4+0], vl[j4*4+1], vl[j4*4+2], vl[j4*4+3]};
      *(float4*)&ktG[sg][srow_l][sdh*16 + (j4 << 2)] = kw;
      *(float4*)&vtG[sg][srow_l][sdh*16 + (j4 << 2)] = vw;
    }
    __syncthreads();
    __builtin_amdgcn_s_setprio(1);
#pragma unroll
    for (int nn = 0; nn < 32; ++nn) {
      float4 k4 = *(const float4*)&ktG[sg][nn][d0];
      float4 v4 = *(const float4*)&vtG[sg][nn][e0];
      float kv_[4] = {k4.x, k4.y, k4.z, k4.w};
      float vv_[4] = {v4.x, v4.y, v4.z, v4.w};
#pragma unroll
      for (int i = 0; i < 4; ++i)
#pragma unroll
        for (int j = 0; j < 4; ++j)
          acc[i][j] = fmaf(kv_[i], vv_[j], acc[i][j]);
    }
    __builtin_amdgcn_s_setprio(0);
    __syncthreads();
  }

  // merge kv partials (overlay on ktG)
  float* mrg = &ktG[0][0][0];
#pragma unroll
  for (int i = 0; i < 4; ++i)
#pragma unroll
    for (int j = 0; j < 4; ++j)
      mrg[sg * 1024 + (d0 + i) * 32 + (e0 + j)] = acc[i][j];
  __syncthreads();
  size_t o = (size_t)(bh * 8 + chunk) * KVP_STRIDE;
  {
    int idx = t << 2;
    float4 r;
    r.x = mrg[idx+0] + mrg[1024+idx+0] + mrg[2048+idx+0] + mrg[3072+idx+0];
    r.y = mrg[idx+1] + mrg[1024+idx+1] + mrg[2048+idx+1] + mrg[3072+idx+1];
    r.z = mrg[idx+2] + mrg[1024+idx+2] + mrg[2048+idx+2] + mrg[3072+idx+2];
    r.w = mrg[idx+3] + mrg[1024+idx+3] + mrg[2048+idx+3] + mrg[3072+idx+3];
    kvp[o + idx + 0] = r.x; kvp[o + idx + 1] = r.y;
    kvp[o + idx + 2] = r.z; kvp[o + idx + 3] = r.w;
  }
  // merge km (overlay on vtG)
  float* kmb = &vtG[0][0][0];
#pragma unroll
  for (int j = 0; j < 16; ++j) kmb[t * 16 + j] = km16[j];
  __syncthreads();
  if (t < 32) {
    int dh = t >> 4, dj = t & 15;
    float ssum = 0.f;
    for (int r = 0; r < 128; ++r) ssum += kmb[((r << 1) + dh) * 16 + dj];
    kvp[o + 1024 + t] = ssum;
  }
  if (t == 0) {
    kvp[o + 1056] = mx_c;
    kvp[o + 1057] = sum_c;
  }
}

// -- opre = ((rope(q) @ kv) * z + lepe) * o; LSE merge fused; 2 rows/thread --
__global__ __launch_bounds__(256) void k_out_combine(
    float* __restrict__ qkvo, const float* __restrict__ kvp,
    const float* __restrict__ cosT, const float* __restrict__ sinT,
    const float* __restrict__ lepe, int b0) {
  __shared__ float kvs[1024];
  __shared__ float kms[32];
  __shared__ float fcs[8];
  int bh = blockIdx.x, chunk = blockIdx.y;   // chunk in [0,8): rows n, n+2048
  int b = bh >> 3, h = bh & 7;
  int t = threadIdx.x;
  if (t == 0) {
    float mxs[8], sums[8];
    float mx = -3.4e38f;
#pragma unroll
    for (int c = 0; c < 8; ++c) {
      size_t o = (size_t)(bh * 8 + c) * KVP_STRIDE;
      mxs[c] = kvp[o + 1056];
      sums[c] = kvp[o + 1057];
      mx = fmaxf(mx, mxs[c]);
    }
    float T = 0.f;
#pragma unroll
    for (int c = 0; c < 8; ++c) T += sums[c] * expf(mxs[c] - mx);
    float invT = 1.0f / T;
#pragma unroll
    for (int c = 0; c < 8; ++c) fcs[c] = expf(mxs[c] - mx) * invT;
  }
  __syncthreads();
  {
    int idx = t << 2;
    size_t o0 = (size_t)(bh * 8) * KVP_STRIDE + idx;
    float4 r = {0.f, 0.f, 0.f, 0.f};
#pragma unroll
    for (int c = 0; c < 8; ++c) {
      float4 p = *(const float4*)&kvp[o0 + (size_t)c * KVP_STRIDE];
      float f = fcs[c];
      r.x += p.x * f; r.y += p.y * f; r.z += p.z * f; r.w += p.w * f;
    }
    *(float4*)&kvs[idx] = r;
    if (t < 32) {
      float s = 0.f;
#pragma unroll
      for (int c = 0; c < 8; ++c)
        s += kvp[(size_t)(bh * 8 + c) * KVP_STRIDE + 1024 + t] * fcs[c];
      kms[t] = s;
    }
  }
  __syncthreads();
  int n1 = (chunk << 8) + t;
  int n2 = n1 + 2048;
  size_t rb1 = (size_t)(b * N + n1) * C4;
  size_t rb2 = (size_t)(b * N + n2) * C4;
  float q1[32], q2[32];
#pragma unroll
  for (int i = 0; i < 8; ++i) {
    float4 a4 = *(const float4*)&qkvo[rb1 + (h << 5) + (i << 2)];
    float4 b4 = *(const float4*)&qkvo[rb2 + (h << 5) + (i << 2)];
    q1[i*4+0] = a4.x; q1[i*4+1] = a4.y; q1[i*4+2] = a4.z; q1[i*4+3] = a4.w;
    q2[i*4+0] = b4.x; q2[i*4+1] = b4.y; q2[i*4+2] = b4.z; q2[i*4+3] = b4.w;
  }
  float dot1 = 0.f, dot2 = 0.f;
#pragma unroll
  for (int dd = 0; dd < 32; ++dd) {
    dot1 += q1[dd] * kms[dd];
    dot2 += q2[dd] * kms[dd];
  }
  float zv1 = 1.0f / (dot1 + 1e-6f);
  float zv2 = 1.0f / (dot2 + 1e-6f);
#pragma unroll
  for (int j = 0; j < 16; ++j) {
    float c1 = cosT[(n1 << 4) + j], s1 = sinT[(n1 << 4) + j];
    float qr = q1[2*j], qi = q1[2*j+1];
    q1[2*j]   = qr * c1 - qi * s1;
    q1[2*j+1] = qr * s1 + qi * c1;
    float c2 = cosT[(n2 << 4) + j], s2 = sinT[(n2 << 4) + j];
    float kr = q2[2*j], ki = q2[2*j+1];
    q2[2*j]   = kr * c2 - ki * s2;
    q2[2*j+1] = kr * s2 + ki * c2;
  }
  size_t oc1 = (size_t)((b0 + b) * N + n1) * C + (h << 5);
  size_t oc2 = (size_t)((b0 + b) * N + n2) * C + (h << 5);
#pragma unroll
  for (int e4 = 0; e4 < 8; ++e4) {
    float a1x = 0, a1y = 0, a1z = 0, a1w = 0;
    float a2x = 0, a2y = 0, a2z = 0, a2w = 0;
#pragma unroll
    for (int dd = 0; dd < 32; ++dd) {
      float4 kv4 = *(const float4*)&kvs[(dd << 5) + (e4 << 2)];
      float qa = q1[dd], qb = q2[dd];
      a1x = fmaf(qa, kv4.x, a1x); a1y = fmaf(qa, kv4.y, a1y);
      a1z = fmaf(qa, kv4.z, a1z); a1w = fmaf(qa, kv4.w, a1w);
      a2x = fmaf(qb, kv4.x, a2x); a2y = fmaf(qb, kv4.y, a2y);
      a2z = fmaf(qb, kv4.z, a2z); a2w = fmaf(qb, kv4.w, a2w);
    }
    float4 lp1 = *(const float4*)&lepe[oc1 + (e4 << 2)];
    float4 ov1 = *(const float4*)&qkvo[rb1 + 768 + (h << 5) + (e4 << 2)];
    float4 r1;
    r1.x = (a1x * zv1 + lp1.x) * ov1.x;
    r1.y = (a1y * zv1 + lp1.y) * ov1.y;
    r1.z = (a1z * zv1 + lp1.z) * ov1.z;
    r1.w = (a1w * zv1 + lp1.w) * ov1.w;
    *(float4*)&qkvo[rb1 + (h << 5) + (e4 << 2)] = r1;
    float4 lp2 = *(const float4*)&lepe[oc2 + (e4 << 2)];
    float4 ov2 = *(const float4*)&qkvo[rb2 + 768 + (h << 5) + (e4 << 2)];
    float4 r2;
    r2.x = (a2x * zv2 + lp2.x) * ov2.x;
    r2.y = (a2y * zv2 + lp2.y) * ov2.y;
    r2.z = (a2z * zv2 + lp2.z) * ov2.z;
    r2.w = (a2w * zv2 + lp2.w) * ov2.w;
    *(float4*)&qkvo[rb2 + (h << 5) + (e4 << 2)] = r2;
  }
}

// ---------------------------------------------------------------------------
static inline size_t ws_bytes_needed(int bpp) {
  size_t pn = (size_t)bpp * N;
  size_t f32c = pn * C4                            // qkvo
              + (size_t)bpp * 32 * 256             // qmean partials
              + (size_t)bpp * NH * 8 * KVP_STRIDE  // kv+km+stats partials
              + (size_t)N * 16 * 2;                // cos/sin
  size_t f16c = (size_t)C * C4 * 2                 // wq T splits
              + (size_t)C * C * 2;                 // wp T splits
  return f32c * 4 + f16c * 2;
}

extern "C" void kernel_launch(void* const* d_in, const int* in_sizes, int n_in,
                              void* d_out, int out_size, void* d_ws, size_t ws_size,
                              hipStream_t stream) {
  const float* x      = (const float*)d_in[0];
  const float* w_qkvo = (const float*)d_in[1];
  const float* b_qkvo = (const float*)d_in[2];
  const float* lepe_w = (const float*)d_in[3];
  const float* lepe_b = (const float*)d_in[4];
  const float* w_proj = (const float*)d_in[5];
  const float* b_proj = (const float*)d_in[6];
  float* out = (float*)d_out;
  float* ws  = (float*)d_ws;

  int bpp = 2;
  if (ws_bytes_needed(16) <= ws_size) bpp = 16;
  else if (ws_bytes_needed(8) <= ws_size) bpp = 8;
  else if (ws_bytes_needed(4) <= ws_size) bpp = 4;

  size_t pn = (size_t)bpp * N;
  int nbh = bpp * NH;
  float* qkvo  = ws;
  float* qpart = qkvo  + pn * C4;
  float* kvp   = qpart + (size_t)bpp * 32 * 256;
  float* cosT  = kvp   + (size_t)nbh * 8 * KVP_STRIDE;
  float* sinT  = cosT  + (size_t)N * 16;
  _Float16* wqh = (_Float16*)(sinT + (size_t)N * 16);
  _Float16* wql = wqh + (size_t)C * C4;
  _Float16* wph = wql + (size_t)C * C4;
  _Float16* wpl = wph + (size_t)C * C;

  k_prologue<<<256 + C4 + C, 256, 0, stream>>>(w_qkvo, w_proj, cosT, sinT,
                                               wqh, wql, wph, wpl);

  for (int b0 = 0; b0 < B; b0 += bpp) {
    // GEMM1: qkvo = x@w_qkvo + b, elu on cols<512, qmean partials fused
    k_gemm_split<<<dim3(pn / 128, C4 / 128), 256, 0, stream>>>(
        x + (size_t)b0 * N * C, C, wqh, wql, b_qkvo, qkvo, C4, 512, qpart);
    // merged: flash kv (nbh*8 blocks) + lepe (bpp*256 blocks)
    int kvN = nbh * 8;
    k_kvflash_lepe<<<kvN + bpp * 256, 256, 0, stream>>>(
        qkvo, qpart, cosT, sinT, kvp, lepe_w, lepe_b, out, b0, kvN);
    k_out_combine<<<dim3(nbh, 8), 256, 0, stream>>>(qkvo, kvp, cosT, sinT, out, b0);
    // GEMM2: out = opre @ w_proj + b (A = f32 opre in qkvo q-slot)
    k_gemm_split<<<dim3(pn / 128, C / 128), 256, 0, stream>>>(
        qkvo, C4, wph, wpl, b_proj, out + (size_t)b0 * N * C, C, 0, nullptr);
  }
}